// Round 3
// baseline (115.901 us; speedup 1.0000x reference)
//
#include <hip/hip_runtime.h>
#include <hip/hip_bf16.h>

// Piecewise GELU (tanh-approx, clamped at |x|=3), fp32 in/out.
// HBM-bound elementwise stream. Specialized compile-time trip count
// (2048 blocks x 256 thr x 32 f32x4 chunks) with unroll-4 so 4
// independent nontemporal float4 loads are in flight per group.

typedef float f32x4 __attribute__((ext_vector_type(4)));

#define CLAMP_V 3.0f
// exponent arg = xc * (C0 + C1*xc^2), with -2*sqrt(2/pi)*log2(e) folded in:
// C0 = -2*0.7978845608*1.4426950409 ; C1 = C0*0.044715
#define PG_C0 -2.3022078893f
#define PG_C1 -0.1029432176f

__device__ __forceinline__ float pgelu(float x) {
    // Clamp the exp-branch input; outside [-3,3] the selects override it.
    float xc = fminf(fmaxf(x, -CLAMP_V), CLAMP_V);
    float x2 = xc * xc;
    // 0.5*x*(1+tanh(i)) == x/(1+exp(-2i)) == x/(1+exp2(xc*(C0+C1*x2)))
    float e = __builtin_amdgcn_exp2f(xc * __builtin_fmaf(PG_C1, x2, PG_C0));
    float mid = xc * __builtin_amdgcn_rcpf(1.0f + e);
    float out = (x <= -CLAMP_V) ? 0.0f : mid;
    out = (x >= CLAMP_V) ? x : out;
    return out;
}

__device__ __forceinline__ f32x4 pgelu4(f32x4 v) {
    f32x4 r;
    r.x = pgelu(v.x);
    r.y = pgelu(v.y);
    r.z = pgelu(v.z);
    r.w = pgelu(v.w);
    return r;
}

// Specialized: compile-time trip count, unroll 4 -> 4 independent NT loads
// (64 B/lane) in flight per unrolled group.
template <int ITERS>
__global__ __launch_bounds__(256) void pgelu_fixed(const f32x4* __restrict__ in,
                                                   f32x4* __restrict__ out) {
    int base = blockIdx.x * blockDim.x + threadIdx.x;
    int stride = gridDim.x * blockDim.x;
#pragma unroll 4
    for (int k = 0; k < ITERS; ++k) {
        int i = base + k * stride;
        f32x4 a = __builtin_nontemporal_load(&in[i]);
        __builtin_nontemporal_store(pgelu4(a), &out[i]);
    }
}

// Generic fallback (any size).
__global__ void pgelu_generic(const f32x4* __restrict__ in,
                              f32x4* __restrict__ out, int n4) {
    int stride = gridDim.x * blockDim.x;
    for (int i = blockIdx.x * blockDim.x + threadIdx.x; i < n4; i += stride) {
        f32x4 a = __builtin_nontemporal_load(&in[i]);
        __builtin_nontemporal_store(pgelu4(a), &out[i]);
    }
}

__global__ void pgelu_tail(const float* __restrict__ in,
                           float* __restrict__ out, int start, int n) {
    int i = start + blockIdx.x * blockDim.x + threadIdx.x;
    if (i < n) out[i] = pgelu(in[i]);
}

extern "C" void kernel_launch(void* const* d_in, const int* in_sizes, int n_in,
                              void* d_out, int out_size, void* d_ws, size_t ws_size,
                              hipStream_t stream) {
    const float* in = (const float*)d_in[0];
    float* out = (float*)d_out;
    int n = in_sizes[0];
    int n4 = n / 4;

    const int block = 256;
    const int grid = 2048;  // 8 blocks/CU x 256 CUs, full occupancy
    const long long total = (long long)grid * block;

    if (n4 > 0 && (n4 % total) == 0 && (n4 / total) == 32) {
        pgelu_fixed<32><<<grid, block, 0, stream>>>((const f32x4*)in, (f32x4*)out);
    } else if (n4 > 0) {
        int g = (n4 + block - 1) / block;
        if (g > grid) g = grid;
        pgelu_generic<<<g, block, 0, stream>>>((const f32x4*)in, (f32x4*)out, n4);
    }

    int rem = n - n4 * 4;
    if (rem > 0) {
        pgelu_tail<<<1, 64, 0, stream>>>(in, out, n4 * 4, n);
    }
}

// Round 4
// 89.645 us; speedup vs baseline: 1.2929x; 1.2929x over previous
//
#include <hip/hip_runtime.h>
#include <hip/hip_bf16.h>

// Piecewise GELU (tanh-approx, clamped at |x|=3), fp32 in/out.
// HBM-bound elementwise stream. Round-2 structure (grouped loads, then
// grouped stores), deepened to 4 independent float4 loads per iteration.
// Plain (cached) loads; nontemporal stores (write-once stream).

typedef float f32x4 __attribute__((ext_vector_type(4)));

#define CLAMP_V 3.0f
// exponent arg = xc * (C0 + C1*xc^2), with -2*sqrt(2/pi)*log2(e) folded in:
// C0 = -2*0.7978845608*1.4426950409 ; C1 = C0*0.044715
#define PG_C0 -2.3022078893f
#define PG_C1 -0.1029432176f

__device__ __forceinline__ float pgelu(float x) {
    // Clamp the exp-branch input; outside [-3,3] the selects override it.
    float xc = fminf(fmaxf(x, -CLAMP_V), CLAMP_V);
    float x2 = xc * xc;
    // 0.5*x*(1+tanh(i)) == x/(1+exp(-2i)) == x/(1+exp2(xc*(C0+C1*x2)))
    float e = __builtin_amdgcn_exp2f(xc * __builtin_fmaf(PG_C1, x2, PG_C0));
    float mid = xc * __builtin_amdgcn_rcpf(1.0f + e);
    float out = (x <= -CLAMP_V) ? 0.0f : mid;
    out = (x >= CLAMP_V) ? x : out;
    return out;
}

__device__ __forceinline__ f32x4 pgelu4(f32x4 v) {
    f32x4 r;
    r.x = pgelu(v.x);
    r.y = pgelu(v.y);
    r.z = pgelu(v.z);
    r.w = pgelu(v.w);
    return r;
}

__global__ void pgelu_kernel_v4(const f32x4* __restrict__ in,
                                f32x4* __restrict__ out, int n4) {
    int stride = gridDim.x * blockDim.x;
    int i = blockIdx.x * blockDim.x + threadIdx.x;
    // 4 independent coalesced loads issued back-to-back, then 4 stores.
    for (; i + 3 * stride < n4; i += 4 * stride) {
        f32x4 a0 = in[i];
        f32x4 a1 = in[i + stride];
        f32x4 a2 = in[i + 2 * stride];
        f32x4 a3 = in[i + 3 * stride];
        __builtin_nontemporal_store(pgelu4(a0), &out[i]);
        __builtin_nontemporal_store(pgelu4(a1), &out[i + stride]);
        __builtin_nontemporal_store(pgelu4(a2), &out[i + 2 * stride]);
        __builtin_nontemporal_store(pgelu4(a3), &out[i + 3 * stride]);
    }
    for (; i < n4; i += stride) {
        f32x4 a = in[i];
        __builtin_nontemporal_store(pgelu4(a), &out[i]);
    }
}

__global__ void pgelu_tail(const float* __restrict__ in,
                           float* __restrict__ out, int start, int n) {
    int i = start + blockIdx.x * blockDim.x + threadIdx.x;
    if (i < n) out[i] = pgelu(in[i]);
}

extern "C" void kernel_launch(void* const* d_in, const int* in_sizes, int n_in,
                              void* d_out, int out_size, void* d_ws, size_t ws_size,
                              hipStream_t stream) {
    const float* in = (const float*)d_in[0];
    float* out = (float*)d_out;
    int n = in_sizes[0];
    int n4 = n / 4;

    const int block = 256;
    // Memory-bound: ~8 blocks/CU x 256 CUs, grid-stride the rest.
    int grid = (n4 + block - 1) / block;
    if (grid > 2048) grid = 2048;
    if (grid < 1) grid = 1;

    pgelu_kernel_v4<<<grid, block, 0, stream>>>((const f32x4*)in, (f32x4*)out, n4);

    int rem = n - n4 * 4;
    if (rem > 0) {
        pgelu_tail<<<1, 64, 0, stream>>>(in, out, n4 * 4, n);
    }
}